// Round 4
// baseline (774.418 us; speedup 1.0000x reference)
//
#include <hip/hip_runtime.h>
#include <stdint.h>

#define N      8192
#define FEAT   512
#define HID    64
#define NH     4
#define C1     256          // NH*HID
#define PCH    80           // per-head c width incl. Z tile (64 data + 16)
#define TC     320          // NH*PCH
#define C2     32           // phase-B c width (16 data + 16 Z tile)
#define IPB    8            // rows per block in k1

typedef __attribute__((ext_vector_type(8))) short bf16x8;
typedef __attribute__((ext_vector_type(4))) float f32x4;
typedef __attribute__((ext_vector_type(4))) uint32_t u32x4;

__device__ __forceinline__ float b2f(uint16_t u){
  uint32_t x = ((uint32_t)u) << 16;
  return __builtin_bit_cast(float, x);
}
__device__ __forceinline__ uint16_t f2b(float f){
  uint32_t x = __builtin_bit_cast(uint32_t, f);
  uint32_t r = (x + 0x7fffu + ((x >> 16) & 1u)) >> 16;
  return (uint16_t)r;
}
// pack two f32 -> bf16x2 (round-half-up: +0x8000, take hi16)
__device__ __forceinline__ uint32_t pack_bf2(float a, float b){
  uint32_t ua = (__builtin_bit_cast(uint32_t, a) + 0x8000u) >> 16;
  uint32_t ub = (__builtin_bit_cast(uint32_t, b) + 0x8000u) & 0xFFFF0000u;
  return ua | ub;
}

// ---------------------------------------------------------------- kA: adj (int 0/1) -> bitmask adjbT[jw][i]
__global__ __launch_bounds__(256) void kA_bits(const int* __restrict__ adj, uint32_t* __restrict__ adjbT){
  int bid = blockIdx.x;               // 8192 blocks
  int iband = bid & 127, jwq = bid >> 7;
  int t = threadIdx.x;
  int i  = iband * 64 + (t & 63);
  int jw = jwq * 4 + (t >> 6);
  const int4* ap = (const int4*)(adj + (size_t)i * N + jw * 32);
  uint32_t w = 0;
  #pragma unroll
  for (int e = 0; e < 8; ++e){
    int4 v = ap[e];
    uint32_t nib = (uint32_t)(v.x & 1) | ((uint32_t)(v.y & 1) << 1)
                 | ((uint32_t)(v.z & 1) << 2) | ((uint32_t)(v.w & 1) << 3);
    w |= nib << (4 * e);
  }
  adjbT[(size_t)jw * N + i] = w;
}

// ---------------------------------------------------------------- k0: Wh -> WhT[k][cc][f]  (fp32)
__global__ void k0_wht(const float* __restrict__ Wh, float* __restrict__ WhT){
  int idx = blockIdx.x * 256 + threadIdx.x;       // 131072 elems
  int k = idx >> 15;
  int r = idx & 32767;
  int cc = r >> 9, f = r & 511;
  WhT[idx] = Wh[k * 32768 + f * 64 + cc];
}

// ---------------------------------------------------------------- k1: H = x @ Wh  (+ f1,f2)
__global__ __launch_bounds__(256) void k1_h(const float* __restrict__ x,
    const float* __restrict__ WhT, const float* __restrict__ ah,
    uint16_t* __restrict__ H, float* __restrict__ f1, float* __restrict__ f2)
{
  __shared__ float4 xs[IPB][128];
  int t = threadIdx.x;
  int i0 = blockIdx.x * IPB;
  for (int r = t; r < IPB * 128; r += 256){
    int ii = r >> 7, o = r & 127;
    xs[ii][o] = *((const float4*)(x + (size_t)(i0 + ii) * FEAT) + o);
  }
  __syncthreads();
  int k = t >> 6, cc = t & 63;
  const float4* wrow = (const float4*)(WhT + k * 32768 + cc * 512);
  float acc[IPB] = {};
  for (int f4 = 0; f4 < 128; ++f4){
    float4 wv = wrow[f4];
    #pragma unroll
    for (int ii = 0; ii < IPB; ++ii){
      float4 xv = xs[ii][f4];
      acc[ii] += xv.x * wv.x + xv.y * wv.y + xv.z * wv.z + xv.w * wv.w;
    }
  }
  float a1 = ah[k * 128 + cc], a2 = ah[k * 128 + 64 + cc];
  #pragma unroll
  for (int ii = 0; ii < IPB; ++ii){
    int i = i0 + ii;
    H[(size_t)i * C1 + t] = f2b(acc[ii]);
    float c1v = acc[ii] * a1, c2v = acc[ii] * a2;
    #pragma unroll
    for (int off = 32; off; off >>= 1){
      c1v += __shfl_down(c1v, off);
      c2v += __shfl_down(c2v, off);
    }
    if (cc == 0){ f1[k * N + i] = c1v; f2[k * N + i] = c2v; }
  }
}

// ---------------------------------------------------------------- kE: f1,f2 -> exp pairs
__global__ void kE_exp(const float* __restrict__ f1, const float* __restrict__ f2,
                       float2* __restrict__ e1p, float2* __restrict__ e2p){
  int idx = blockIdx.x * 256 + threadIdx.x;      // 32768
  float v1 = f1[idx], v2 = f2[idx];
  e1p[idx] = make_float2(__expf(v1), __expf(0.2f * v1));
  e2p[idx] = make_float2(__expf(v2), __expf(0.2f * v2));
}

// ---------------------------------------------------------------- k2a: HT[k][p<64][i] = H[i][k*64+p]
__global__ void k2a_htT(const uint16_t* __restrict__ H, uint16_t* __restrict__ HT){
  __shared__ uint16_t tile[64][65];
  int bid = blockIdx.x;           // 128 i-tiles x 4 heads
  int k = bid & 3, it = bid >> 2;
  int i0 = it * 64;
  int t = threadIdx.x;
  #pragma unroll
  for (int r = 0; r < 4; ++r){
    int ii = r * 16 + (t >> 4);
    int pp = (t & 15) * 4;
    uint2 v = *(const uint2*)(H + (size_t)(i0 + ii) * C1 + k * 64 + pp);
    const uint16_t* s = (const uint16_t*)&v;
    tile[pp + 0][ii] = s[0]; tile[pp + 1][ii] = s[1];
    tile[pp + 2][ii] = s[2]; tile[pp + 3][ii] = s[3];
  }
  __syncthreads();
  #pragma unroll
  for (int r = 0; r < 4; ++r){
    int pp = r * 16 + (t >> 4);
    int ii = (t & 15) * 4;
    uint2 v;
    uint16_t* s = (uint16_t*)&v;
    s[0] = tile[pp][ii + 0]; s[1] = tile[pp][ii + 1];
    s[2] = tile[pp][ii + 2]; s[3] = tile[pp][ii + 3];
    *(uint2*)(HT + (size_t)k * (PCH * N) + (size_t)pp * N + i0 + ii) = v;
  }
}

// ---------------------------------------------------------------- k2b: HT rows 64..79 (ones + zeros)
__global__ void k2b_fill(uint16_t* __restrict__ HT){
  int fidx = blockIdx.x * 256 + threadIdx.x;      // 65536 uint4 units
  int k = fidx >> 14;
  int rem = fidx & 16383;
  int p = 64 + (rem >> 10);
  int i0 = (rem & 1023) << 3;
  uint32_t w = (p == 64) ? 0x3F803F80u : 0u;
  uint4 v = {w, w, w, w};
  *((uint4*)(HT + (size_t)k * (PCH * N) + (size_t)p * N + i0)) = v;
}

// ---------------------------------------------------------------- k3: phase-A, barrier-free wave-autonomous
// block = (js, head, 128 i-rows); 4 waves x 32 rows. 1024 blocks x 256 th.
__global__ __launch_bounds__(256) void k3_attA(const uint32_t* __restrict__ adjbT,
    const uint16_t* __restrict__ HT, const float2* __restrict__ e1p,
    const float2* __restrict__ e2p, float* __restrict__ accA)
{
  const int t    = threadIdx.x;
  const int bid  = blockIdx.x;
  const int js   = bid & 3;
  const int head = (bid >> 2) & 3;
  const int ig   = bid >> 4;             // 0..63
  const int w    = t >> 6;
  const int lane = t & 63;
  const int m    = lane & 15;
  const int q    = lane >> 4;
  const int gi0  = ig * 128 + w * 32;

  float2 e1v0 = e1p[(size_t)head * N + gi0 + m];
  float2 e1v1 = e1p[(size_t)head * N + gi0 + 16 + m];

  const uint16_t* Hbase = HT + (size_t)head * (PCH * N) + (size_t)m * N + q * 8;
  const float2*   E2b   = e2p + (size_t)head * N;
  const uint32_t* Mb0   = adjbT + gi0 + m;
  const uint32_t* Mb1   = adjbT + gi0 + 16 + m;

  f32x4 acc[2][5] = {};

  for (int jc = 0; jc < 64; ++jc){
    const int gj = js * 2048 + jc * 32;
    const int jw = gj >> 5;
    // per-lane loads (no LDS, no barrier — pipelined across iterations)
    const float4* E2 = (const float4*)(E2b + gj);
    float4 ev[4];
    #pragma unroll
    for (int r = 0; r < 4; ++r) ev[r] = E2[q * 4 + r];
    uint32_t mw0 = Mb0[(size_t)jw * N];
    uint32_t mw1 = Mb1[(size_t)jw * N];
    bf16x8 bq[5];
    #pragma unroll
    for (int ct = 0; ct < 5; ++ct)
      bq[ct] = *(const bf16x8*)(Hbase + (size_t)(ct * 16) * N + gj);

    uint32_t sh0 = mw0 >> (q * 8);
    uint32_t sh1 = mw1 >> (q * 8);
    u32x4 pk0, pk1;
    #pragma unroll
    for (int p = 0; p < 4; ++p){
      float4 v = ev[p];
      float wa0 = fmaxf(e1v0.x * v.x, e1v0.y * v.y);
      float wb0 = fmaxf(e1v0.x * v.z, e1v0.y * v.w);
      wa0 = ((sh0 >> (2 * p)) & 1u) ? wa0 : 0.f;
      wb0 = ((sh0 >> (2 * p)) & 2u) ? wb0 : 0.f;
      pk0[p] = pack_bf2(wa0, wb0);
      float wa1 = fmaxf(e1v1.x * v.x, e1v1.y * v.y);
      float wb1 = fmaxf(e1v1.x * v.z, e1v1.y * v.w);
      wa1 = ((sh1 >> (2 * p)) & 1u) ? wa1 : 0.f;
      wb1 = ((sh1 >> (2 * p)) & 2u) ? wb1 : 0.f;
      pk1[p] = pack_bf2(wa1, wb1);
    }
    bf16x8 af0 = __builtin_bit_cast(bf16x8, pk0);
    bf16x8 af1 = __builtin_bit_cast(bf16x8, pk1);
    #pragma unroll
    for (int ct = 0; ct < 5; ++ct){
      acc[0][ct] = __builtin_amdgcn_mfma_f32_16x16x32_bf16(af0, bq[ct], acc[0][ct], 0, 0, 0);
      acc[1][ct] = __builtin_amdgcn_mfma_f32_16x16x32_bf16(af1, bq[ct], acc[1][ct], 0, 0, 0);
    }
  }

  #pragma unroll
  for (int it = 0; it < 2; ++it)
    #pragma unroll
    for (int ct = 0; ct < 5; ++ct)
      #pragma unroll
      for (int reg = 0; reg < 4; ++reg){
        int gi = gi0 + it * 16 + q * 4 + reg;
        int c  = head * PCH + ct * 16 + m;
        accA[((size_t)js * N + gi) * TC + c] = acc[it][ct][reg];
      }
}

// ---------------------------------------------------------------- k4: reduce partials -> xcat (lrelu 0.01)
__global__ void k4_redA(const float* __restrict__ accA, uint16_t* __restrict__ xcat){
  int i = blockIdx.x;
  int t = threadIdx.x;
  int k = t >> 6, cc = t & 63;
  size_t base = (size_t)i * TC + k * PCH;
  float v = 0.f, Z = 0.f;
  #pragma unroll
  for (int js = 0; js < 4; ++js){
    const float* p = accA + (size_t)js * N * TC + base;
    v += p[cc];
    Z += p[64];
  }
  float r = v / Z;
  xcat[(size_t)i * C1 + t] = f2b(fmaxf(r, 0.01f * r));
}

// ---------------------------------------------------------------- k5: h2 = xcat@Wo, exp pairs, h2T(+ones)
__global__ __launch_bounds__(256) void k5_h2(const uint16_t* __restrict__ xcat,
    const float* __restrict__ Wo, const float* __restrict__ ao,
    uint16_t* __restrict__ h2T, float2* __restrict__ e1op, float2* __restrict__ e2op)
{
  __shared__ uint16_t xs[16][256];
  int t = threadIdx.x;
  int i0 = blockIdx.x * 16;
  #pragma unroll
  for (int r = 0; r < 2; ++r){
    int idx = t + 256 * r;
    int ii = idx >> 5, o4 = idx & 31;
    *(uint4*)&xs[ii][o4 * 8] = *(const uint4*)(xcat + (size_t)(i0 + ii) * C1 + o4 * 8);
  }
  __syncthreads();
  int ii = t >> 4, c = t & 15;
  float acc = 0.f;
  for (int f = 0; f < 256; ++f)
    acc += b2f(xs[ii][f]) * Wo[f * 16 + c];
  int i = i0 + ii;
  h2T[(size_t)c * N + i] = f2b(acc);
  float u1 = acc * ao[c];
  float u2 = acc * ao[16 + c];
  #pragma unroll
  for (int off = 8; off; off >>= 1){
    u1 += __shfl_down(u1, off, 16);
    u2 += __shfl_down(u2, off, 16);
  }
  if (c == 0){
    e1op[i] = make_float2(__expf(u1), __expf(0.2f * u1));
    e2op[i] = make_float2(__expf(u2), __expf(0.2f * u2));
  }
  if (t < 16) h2T[(size_t)16 * N + i0 + t] = 0x3F80;      // ones row
  if (t < 240){                                            // zero rows 17..31
    int p = 17 + t / 16, io = t % 16;
    h2T[(size_t)p * N + i0 + io] = 0;
  }
}

// ---------------------------------------------------------------- k6: phase-B, barrier-free wave-autonomous
// block = (js of 8, 2 itiles); 2 waves x 16 rows. 2048 blocks x 128 th.
__global__ __launch_bounds__(128) void k6_attB(const uint32_t* __restrict__ adjbT,
    const uint16_t* __restrict__ h2T, const float2* __restrict__ e1op,
    const float2* __restrict__ e2op, float* __restrict__ accB)
{
  const int t    = threadIdx.x;
  const int bid  = blockIdx.x;
  const int js   = bid & 7;
  const int ig   = bid >> 3;             // 0..255
  const int w    = t >> 6;
  const int lane = t & 63;
  const int m    = lane & 15;
  const int q    = lane >> 4;
  const int gi0  = (ig * 2 + w) * 16;

  float2 e1v = e1op[gi0 + m];
  const uint16_t* Hbase = h2T + (size_t)m * N + q * 8;
  const uint32_t* Mb    = adjbT + gi0 + m;

  f32x4 acc[2] = {};

  #pragma unroll 2
  for (int jc = 0; jc < 32; ++jc){
    const int gj = js * 1024 + jc * 32;
    const int jw = gj >> 5;
    const float4* E2 = (const float4*)(e2op + gj);
    float4 ev[4];
    #pragma unroll
    for (int r = 0; r < 4; ++r) ev[r] = E2[q * 4 + r];
    uint32_t mw = Mb[(size_t)jw * N];
    bf16x8 bq0 = *(const bf16x8*)(Hbase + gj);
    bf16x8 bq1 = *(const bf16x8*)(Hbase + (size_t)16 * N + gj);

    uint32_t sh = mw >> (q * 8);
    u32x4 pk;
    #pragma unroll
    for (int p = 0; p < 4; ++p){
      float4 v = ev[p];
      float wa = fmaxf(e1v.x * v.x, e1v.y * v.y);
      float wb = fmaxf(e1v.x * v.z, e1v.y * v.w);
      wa = ((sh >> (2 * p)) & 1u) ? wa : 0.f;
      wb = ((sh >> (2 * p)) & 2u) ? wb : 0.f;
      pk[p] = pack_bf2(wa, wb);
    }
    bf16x8 af = __builtin_bit_cast(bf16x8, pk);
    acc[0] = __builtin_amdgcn_mfma_f32_16x16x32_bf16(af, bq0, acc[0], 0, 0, 0);
    acc[1] = __builtin_amdgcn_mfma_f32_16x16x32_bf16(af, bq1, acc[1], 0, 0, 0);
  }

  #pragma unroll
  for (int ct = 0; ct < 2; ++ct)
    #pragma unroll
    for (int reg = 0; reg < 4; ++reg){
      int gi = gi0 + q * 4 + reg;
      accB[((size_t)js * N + gi) * C2 + ct * 16 + m] = acc[ct][reg];
    }
}

// ---------------------------------------------------------------- k7: reduce -> out (fp32)
__global__ void k7_redB(const float* __restrict__ accB, float* __restrict__ out){
  int idx = blockIdx.x * 256 + threadIdx.x;   // 131072
  int i = idx >> 4, c = idx & 15;
  float v = 0.f, Z = 0.f;
  #pragma unroll
  for (int js = 0; js < 8; ++js){
    const float* p = accB + ((size_t)js * N + i) * C2;
    v += p[c];
    Z += p[16];
  }
  out[idx] = v / Z;
}

// ================================================================ launch
extern "C" void kernel_launch(void* const* d_in, const int* in_sizes, int n_in,
                              void* d_out, int out_size, void* d_ws, size_t ws_size,
                              hipStream_t stream)
{
  const float* x   = (const float*)d_in[0];
  const int*   adj = (const int*)d_in[1];
  const float* Wh  = (const float*)d_in[2];
  const float* ah  = (const float*)d_in[3];
  const float* Wo  = (const float*)d_in[4];
  const float* ao  = (const float*)d_in[5];
  float* out = (float*)d_out;

  char* ws = (char*)d_ws;
  float*    WhT   = (float*)   (ws);                 // 512 KB
  uint16_t* H     = (uint16_t*)(ws + 524288);        // 4 MB
  uint16_t* HT    = (uint16_t*)(ws + 4718592);       // 5 MB   [4][80][8192] bf16
  float*    f1    = (float*)   (ws + 9961472);       // 128 KB
  float*    f2    = (float*)   (ws + 10092544);      // 128 KB
  float*    accA  = (float*)   (ws + 10223616);      // 40 MB  [4][8192][320]
  uint16_t* xcat  = (uint16_t*)(ws + 52166656);      // 4 MB
  uint16_t* h2T   = (uint16_t*)(ws + 56360960);      // 512 KB [32][8192] bf16
  float2*   e1op  = (float2*)  (ws + 56885248);      // 64 KB
  float2*   e2op  = (float2*)  (ws + 56950784);      // 64 KB
  float*    accB  = (float*)   (ws + 57016320);      // 8 MB   [8][8192][32]
  float2*   e1p   = (float2*)  (ws + 65404928);      // 256 KB [4][8192]
  float2*   e2p   = (float2*)  (ws + 65667072);      // 256 KB
  uint32_t* adjbT = (uint32_t*)(ws + 65929216);      // 8 MB   [256][8192]  (end 74317824)

  hipLaunchKernelGGL(kA_bits,  dim3(8192), dim3(256), 0, stream, adj, adjbT);
  hipLaunchKernelGGL(k0_wht,   dim3(512),  dim3(256), 0, stream, Wh, WhT);
  hipLaunchKernelGGL(k1_h,     dim3(1024), dim3(256), 0, stream, x, WhT, ah, H, f1, f2);
  hipLaunchKernelGGL(kE_exp,   dim3(128),  dim3(256), 0, stream, f1, f2, e1p, e2p);
  hipLaunchKernelGGL(k2a_htT,  dim3(512),  dim3(256), 0, stream, H, HT);
  hipLaunchKernelGGL(k2b_fill, dim3(256),  dim3(256), 0, stream, HT);
  hipLaunchKernelGGL(k3_attA,  dim3(1024), dim3(256), 0, stream, adjbT, HT, e1p, e2p, accA);
  hipLaunchKernelGGL(k4_redA,  dim3(8192), dim3(256), 0, stream, accA, xcat);
  hipLaunchKernelGGL(k5_h2,    dim3(512),  dim3(256), 0, stream, xcat, Wo, ao, h2T, e1op, e2op);
  hipLaunchKernelGGL(k6_attB,  dim3(2048), dim3(128), 0, stream, adjbT, h2T, e1op, e2op, accB);
  hipLaunchKernelGGL(k7_redB,  dim3(512),  dim3(256), 0, stream, accB, out);
}

// Round 5
// 662.852 us; speedup vs baseline: 1.1683x; 1.1683x over previous
//
#include <hip/hip_runtime.h>
#include <stdint.h>

#define N      8192
#define FEAT   512
#define HID    64
#define NH     4
#define C1     256          // NH*HID
#define PCH    80           // per-head c width incl. Z tile (64 data + 16)
#define TC     320          // NH*PCH
#define C2     32           // phase-B c width (16 data + 16 Z tile)
#define IPB    8            // rows per block in k1

typedef __attribute__((ext_vector_type(8))) short bf16x8;
typedef __attribute__((ext_vector_type(4))) float f32x4;
typedef __attribute__((ext_vector_type(4))) uint32_t u32x4;

__device__ __forceinline__ float b2f(uint16_t u){
  uint32_t x = ((uint32_t)u) << 16;
  return __builtin_bit_cast(float, x);
}
__device__ __forceinline__ uint16_t f2b(float f){
  uint32_t x = __builtin_bit_cast(uint32_t, f);
  uint32_t r = (x + 0x7fffu + ((x >> 16) & 1u)) >> 16;
  return (uint16_t)r;
}
// pack two f32 -> bf16x2 (round-half-up: +0x8000, take hi16)
__device__ __forceinline__ uint32_t pack_bf2(float a, float b){
  uint32_t ua = (__builtin_bit_cast(uint32_t, a) + 0x8000u) >> 16;
  uint32_t ub = (__builtin_bit_cast(uint32_t, b) + 0x8000u) & 0xFFFF0000u;
  return ua | ub;
}

// ---------------------------------------------------------------- kA: adj (int 0/1) -> bitmask adjbT[jw][i]
__global__ __launch_bounds__(256) void kA_bits(const int* __restrict__ adj, uint32_t* __restrict__ adjbT){
  int bid = blockIdx.x;               // 8192 blocks
  int iband = bid & 127, jwq = bid >> 7;
  int t = threadIdx.x;
  int i  = iband * 64 + (t & 63);
  int jw = jwq * 4 + (t >> 6);
  const int4* ap = (const int4*)(adj + (size_t)i * N + jw * 32);
  uint32_t w = 0;
  #pragma unroll
  for (int e = 0; e < 8; ++e){
    int4 v = ap[e];
    uint32_t nib = (uint32_t)(v.x & 1) | ((uint32_t)(v.y & 1) << 1)
                 | ((uint32_t)(v.z & 1) << 2) | ((uint32_t)(v.w & 1) << 3);
    w |= nib << (4 * e);
  }
  adjbT[(size_t)jw * N + i] = w;
}

// ---------------------------------------------------------------- k0: Wh -> WhT[k][cc][f]  (fp32)
__global__ void k0_wht(const float* __restrict__ Wh, float* __restrict__ WhT){
  int idx = blockIdx.x * 256 + threadIdx.x;       // 131072 elems
  int k = idx >> 15;
  int r = idx & 32767;
  int cc = r >> 9, f = r & 511;
  WhT[idx] = Wh[k * 32768 + f * 64 + cc];
}

// ---------------------------------------------------------------- k1: H = x @ Wh  (+ f1,f2)
// x reads are wave-uniform (block-row + compile-time ii) -> scalar/L1-broadcast, no LDS pipe.
__global__ __launch_bounds__(256) void k1_h(const float* __restrict__ x,
    const float* __restrict__ WhT, const float* __restrict__ ah,
    uint16_t* __restrict__ H, float* __restrict__ f1, float* __restrict__ f2)
{
  int t = threadIdx.x;
  int i0 = blockIdx.x * IPB;
  int k = t >> 6, cc = t & 63;
  const float4* wrow = (const float4*)(WhT + k * 32768 + cc * 512);
  const float4* xr[IPB];
  #pragma unroll
  for (int ii = 0; ii < IPB; ++ii)
    xr[ii] = (const float4*)(x + (size_t)(i0 + ii) * FEAT);
  float acc[IPB] = {};
  #pragma unroll 2
  for (int f4 = 0; f4 < 128; ++f4){
    float4 wv = wrow[f4];
    #pragma unroll
    for (int ii = 0; ii < IPB; ++ii){
      float4 xv = xr[ii][f4];
      acc[ii] += xv.x * wv.x + xv.y * wv.y + xv.z * wv.z + xv.w * wv.w;
    }
  }
  float a1 = ah[k * 128 + cc], a2 = ah[k * 128 + 64 + cc];
  #pragma unroll
  for (int ii = 0; ii < IPB; ++ii){
    int i = i0 + ii;
    H[(size_t)i * C1 + t] = f2b(acc[ii]);
    float c1v = acc[ii] * a1, c2v = acc[ii] * a2;
    #pragma unroll
    for (int off = 32; off; off >>= 1){
      c1v += __shfl_down(c1v, off);
      c2v += __shfl_down(c2v, off);
    }
    if (cc == 0){ f1[k * N + i] = c1v; f2[k * N + i] = c2v; }
  }
}

// ---------------------------------------------------------------- kE: f1,f2 -> exp pairs
__global__ void kE_exp(const float* __restrict__ f1, const float* __restrict__ f2,
                       float2* __restrict__ e1p, float2* __restrict__ e2p){
  int idx = blockIdx.x * 256 + threadIdx.x;      // 32768
  float v1 = f1[idx], v2 = f2[idx];
  e1p[idx] = make_float2(__expf(v1), __expf(0.2f * v1));
  e2p[idx] = make_float2(__expf(v2), __expf(0.2f * v2));
}

// ---------------------------------------------------------------- k2a: HT[k][p<64][i] = H[i][k*64+p]
__global__ void k2a_htT(const uint16_t* __restrict__ H, uint16_t* __restrict__ HT){
  __shared__ uint16_t tile[64][65];
  int bid = blockIdx.x;           // 128 i-tiles x 4 heads
  int k = bid & 3, it = bid >> 2;
  int i0 = it * 64;
  int t = threadIdx.x;
  #pragma unroll
  for (int r = 0; r < 4; ++r){
    int ii = r * 16 + (t >> 4);
    int pp = (t & 15) * 4;
    uint2 v = *(const uint2*)(H + (size_t)(i0 + ii) * C1 + k * 64 + pp);
    const uint16_t* s = (const uint16_t*)&v;
    tile[pp + 0][ii] = s[0]; tile[pp + 1][ii] = s[1];
    tile[pp + 2][ii] = s[2]; tile[pp + 3][ii] = s[3];
  }
  __syncthreads();
  #pragma unroll
  for (int r = 0; r < 4; ++r){
    int pp = r * 16 + (t >> 4);
    int ii = (t & 15) * 4;
    uint2 v;
    uint16_t* s = (uint16_t*)&v;
    s[0] = tile[pp][ii + 0]; s[1] = tile[pp][ii + 1];
    s[2] = tile[pp][ii + 2]; s[3] = tile[pp][ii + 3];
    *(uint2*)(HT + (size_t)k * (PCH * N) + (size_t)pp * N + i0 + ii) = v;
  }
}

// ---------------------------------------------------------------- k2b: HT rows 64..79 (ones + zeros)
__global__ void k2b_fill(uint16_t* __restrict__ HT){
  int fidx = blockIdx.x * 256 + threadIdx.x;      // 65536 uint4 units
  int k = fidx >> 14;
  int rem = fidx & 16383;
  int p = 64 + (rem >> 10);
  int i0 = (rem & 1023) << 3;
  uint32_t w = (p == 64) ? 0x3F803F80u : 0u;
  uint4 v = {w, w, w, w};
  *((uint4*)(HT + (size_t)k * (PCH * N) + (size_t)p * N + i0)) = v;
}

// ---------------------------------------------------------------- k3: phase-A, wave = 64 i-rows, reg-rotated pipeline
// grid: 32 ibl x 4 heads x 4 js = 512 blocks x 256 th (4 waves x 64 rows)
__global__ __launch_bounds__(256, 2) void k3_attA(const uint32_t* __restrict__ adjbT,
    const uint16_t* __restrict__ HT, const float2* __restrict__ e1p,
    const float2* __restrict__ e2p, float* __restrict__ accA)
{
  const int t    = threadIdx.x;
  const int bid  = blockIdx.x;
  const int js   = bid & 3;
  const int head = (bid >> 2) & 3;
  const int ibl  = bid >> 4;             // 0..31
  const int w    = t >> 6;
  const int lane = t & 63;
  const int m    = lane & 15;
  const int q    = lane >> 4;
  const int gi0  = ibl * 256 + w * 64;

  float2 e1v[4];
  #pragma unroll
  for (int r = 0; r < 4; ++r)
    e1v[r] = e1p[(size_t)head * N + gi0 + r * 16 + m];

  const uint16_t* Hbase = HT + (size_t)head * (PCH * N) + (size_t)m * N + q * 8;
  const float2*   E2b   = e2p + (size_t)head * N;
  const uint32_t* Mb    = adjbT + gi0 + m;

  f32x4 acc[4][5] = {};

  float4   ev[2][4];
  uint32_t mw[2][4];
  bf16x8   bq[2][5];

  auto load_set = [&](int buf, int jc){
    const int gj = js * 2048 + jc * 32;
    const int jw = gj >> 5;
    const float4* E2 = (const float4*)(E2b + gj);
    #pragma unroll
    for (int r2 = 0; r2 < 4; ++r2) ev[buf][r2] = E2[q * 4 + r2];
    #pragma unroll
    for (int r = 0; r < 4; ++r) mw[buf][r] = Mb[(size_t)jw * N + r * 16];
    #pragma unroll
    for (int ct = 0; ct < 5; ++ct)
      bq[buf][ct] = *(const bf16x8*)(Hbase + (size_t)(ct * 16) * N + gj);
  };
  auto compute = [&](int buf){
    #pragma unroll
    for (int r = 0; r < 4; ++r){
      uint32_t sh = mw[buf][r] >> (q * 8);
      u32x4 pk;
      #pragma unroll
      for (int p = 0; p < 4; ++p){
        float4 v = ev[buf][p];
        float wa = fmaxf(e1v[r].x * v.x, e1v[r].y * v.y);
        float wb = fmaxf(e1v[r].x * v.z, e1v[r].y * v.w);
        wa = ((sh >> (2 * p)) & 1u) ? wa : 0.f;
        wb = ((sh >> (2 * p)) & 2u) ? wb : 0.f;
        pk[p] = pack_bf2(wa, wb);
      }
      bf16x8 af = __builtin_bit_cast(bf16x8, pk);
      #pragma unroll
      for (int ct = 0; ct < 5; ++ct)
        acc[r][ct] = __builtin_amdgcn_mfma_f32_16x16x32_bf16(af, bq[buf][ct], acc[r][ct], 0, 0, 0);
    }
  };

  load_set(0, 0);
  for (int jc = 0; jc < 64; jc += 2){
    load_set(1, jc + 1);
    compute(0);
    load_set(0, jc + 2 < 64 ? jc + 2 : 63);   // last one is a harmless dummy reload
    compute(1);
  }

  #pragma unroll
  for (int r = 0; r < 4; ++r)
    #pragma unroll
    for (int ct = 0; ct < 5; ++ct)
      #pragma unroll
      for (int reg = 0; reg < 4; ++reg){
        int gi = gi0 + r * 16 + q * 4 + reg;
        int c  = head * PCH + ct * 16 + m;
        accA[((size_t)js * N + gi) * TC + c] = acc[r][ct][reg];
      }
}

// ---------------------------------------------------------------- k4: reduce partials -> xcat (lrelu 0.01)
__global__ void k4_redA(const float* __restrict__ accA, uint16_t* __restrict__ xcat){
  int i = blockIdx.x;
  int t = threadIdx.x;
  int k = t >> 6, cc = t & 63;
  size_t base = (size_t)i * TC + k * PCH;
  float v = 0.f, Z = 0.f;
  #pragma unroll
  for (int js = 0; js < 4; ++js){
    const float* p = accA + (size_t)js * N * TC + base;
    v += p[cc];
    Z += p[64];
  }
  float r = v / Z;
  xcat[(size_t)i * C1 + t] = f2b(fmaxf(r, 0.01f * r));
}

// ---------------------------------------------------------------- k5: h2 = xcat@Wo, exp pairs, h2T(+ones)
__global__ __launch_bounds__(256) void k5_h2(const uint16_t* __restrict__ xcat,
    const float* __restrict__ Wo, const float* __restrict__ ao,
    uint16_t* __restrict__ h2T, float2* __restrict__ e1op, float2* __restrict__ e2op)
{
  __shared__ uint16_t xs[16][256];
  int t = threadIdx.x;
  int i0 = blockIdx.x * 16;
  #pragma unroll
  for (int r = 0; r < 2; ++r){
    int idx = t + 256 * r;
    int ii = idx >> 5, o4 = idx & 31;
    *(uint4*)&xs[ii][o4 * 8] = *(const uint4*)(xcat + (size_t)(i0 + ii) * C1 + o4 * 8);
  }
  __syncthreads();
  int ii = t >> 4, c = t & 15;
  float acc = 0.f;
  for (int f = 0; f < 256; ++f)
    acc += b2f(xs[ii][f]) * Wo[f * 16 + c];
  int i = i0 + ii;
  h2T[(size_t)c * N + i] = f2b(acc);
  float u1 = acc * ao[c];
  float u2 = acc * ao[16 + c];
  #pragma unroll
  for (int off = 8; off; off >>= 1){
    u1 += __shfl_down(u1, off, 16);
    u2 += __shfl_down(u2, off, 16);
  }
  if (c == 0){
    e1op[i] = make_float2(__expf(u1), __expf(0.2f * u1));
    e2op[i] = make_float2(__expf(u2), __expf(0.2f * u2));
  }
  if (t < 16) h2T[(size_t)16 * N + i0 + t] = 0x3F80;      // ones row
  if (t < 240){                                            // zero rows 17..31
    int p = 17 + t / 16, io = t % 16;
    h2T[(size_t)p * N + i0 + io] = 0;
  }
}

// ---------------------------------------------------------------- k6: phase-B, wave = 32 i-rows, reg-rotated pipeline
// grid: 64 ibl x 8 js = 512 blocks x 256 th (4 waves x 32 rows)
__global__ __launch_bounds__(256, 3) void k6_attB(const uint32_t* __restrict__ adjbT,
    const uint16_t* __restrict__ h2T, const float2* __restrict__ e1op,
    const float2* __restrict__ e2op, float* __restrict__ accB)
{
  const int t    = threadIdx.x;
  const int bid  = blockIdx.x;
  const int js   = bid & 7;
  const int ibl  = bid >> 3;             // 0..63
  const int w    = t >> 6;
  const int lane = t & 63;
  const int m    = lane & 15;
  const int q    = lane >> 4;
  const int gi0  = ibl * 128 + w * 32;

  float2 e1v[2];
  #pragma unroll
  for (int r = 0; r < 2; ++r)
    e1v[r] = e1op[gi0 + r * 16 + m];

  const uint16_t* Hbase = h2T + (size_t)m * N + q * 8;
  const uint32_t* Mb    = adjbT + gi0 + m;

  f32x4 acc[2][2] = {};

  float4   ev[2][4];
  uint32_t mw[2][2];
  bf16x8   bq[2][2];

  auto load_set = [&](int buf, int jc){
    const int gj = js * 1024 + jc * 32;
    const int jw = gj >> 5;
    const float4* E2 = (const float4*)(e2op + gj);
    #pragma unroll
    for (int r2 = 0; r2 < 4; ++r2) ev[buf][r2] = E2[q * 4 + r2];
    #pragma unroll
    for (int r = 0; r < 2; ++r) mw[buf][r] = Mb[(size_t)jw * N + r * 16];
    #pragma unroll
    for (int ct = 0; ct < 2; ++ct)
      bq[buf][ct] = *(const bf16x8*)(Hbase + (size_t)(ct * 16) * N + gj);
  };
  auto compute = [&](int buf){
    #pragma unroll
    for (int r = 0; r < 2; ++r){
      uint32_t sh = mw[buf][r] >> (q * 8);
      u32x4 pk;
      #pragma unroll
      for (int p = 0; p < 4; ++p){
        float4 v = ev[buf][p];
        float wa = fmaxf(e1v[r].x * v.x, e1v[r].y * v.y);
        float wb = fmaxf(e1v[r].x * v.z, e1v[r].y * v.w);
        wa = ((sh >> (2 * p)) & 1u) ? wa : 0.f;
        wb = ((sh >> (2 * p)) & 2u) ? wb : 0.f;
        pk[p] = pack_bf2(wa, wb);
      }
      bf16x8 af = __builtin_bit_cast(bf16x8, pk);
      #pragma unroll
      for (int ct = 0; ct < 2; ++ct)
        acc[r][ct] = __builtin_amdgcn_mfma_f32_16x16x32_bf16(af, bq[buf][ct], acc[r][ct], 0, 0, 0);
    }
  };

  load_set(0, 0);
  for (int jc = 0; jc < 32; jc += 2){
    load_set(1, jc + 1);
    compute(0);
    load_set(0, jc + 2 < 32 ? jc + 2 : 31);
    compute(1);
  }

  #pragma unroll
  for (int r = 0; r < 2; ++r)
    #pragma unroll
    for (int ct = 0; ct < 2; ++ct)
      #pragma unroll
      for (int reg = 0; reg < 4; ++reg){
        int gi = gi0 + r * 16 + q * 4 + reg;
        accB[((size_t)js * N + gi) * C2 + ct * 16 + m] = acc[r][ct][reg];
      }
}

// ---------------------------------------------------------------- k7: reduce -> out (fp32)
__global__ void k7_redB(const float* __restrict__ accB, float* __restrict__ out){
  int idx = blockIdx.x * 256 + threadIdx.x;   // 131072
  int i = idx >> 4, c = idx & 15;
  float v = 0.f, Z = 0.f;
  #pragma unroll
  for (int js = 0; js < 8; ++js){
    const float* p = accB + ((size_t)js * N + i) * C2;
    v += p[c];
    Z += p[16];
  }
  out[idx] = v / Z;
}

// ================================================================ launch
extern "C" void kernel_launch(void* const* d_in, const int* in_sizes, int n_in,
                              void* d_out, int out_size, void* d_ws, size_t ws_size,
                              hipStream_t stream)
{
  const float* x   = (const float*)d_in[0];
  const int*   adj = (const int*)d_in[1];
  const float* Wh  = (const float*)d_in[2];
  const float* ah  = (const float*)d_in[3];
  const float* Wo  = (const float*)d_in[4];
  const float* ao  = (const float*)d_in[5];
  float* out = (float*)d_out;

  char* ws = (char*)d_ws;
  float*    WhT   = (float*)   (ws);                 // 512 KB
  uint16_t* H     = (uint16_t*)(ws + 524288);        // 4 MB
  uint16_t* HT    = (uint16_t*)(ws + 4718592);       // 5 MB   [4][80][8192] bf16
  float*    f1    = (float*)   (ws + 9961472);       // 128 KB
  float*    f2    = (float*)   (ws + 10092544);      // 128 KB
  float*    accA  = (float*)   (ws + 10223616);      // 40 MB  [4][8192][320]
  uint16_t* xcat  = (uint16_t*)(ws + 52166656);      // 4 MB
  uint16_t* h2T   = (uint16_t*)(ws + 56360960);      // 512 KB [32][8192] bf16
  float2*   e1op  = (float2*)  (ws + 56885248);      // 64 KB
  float2*   e2op  = (float2*)  (ws + 56950784);      // 64 KB
  float*    accB  = (float*)   (ws + 57016320);      // 8 MB   [8][8192][32]
  float2*   e1p   = (float2*)  (ws + 65404928);      // 256 KB [4][8192]
  float2*   e2p   = (float2*)  (ws + 65667072);      // 256 KB
  uint32_t* adjbT = (uint32_t*)(ws + 65929216);      // 8 MB   [256][8192]  (end 74317824)

  hipLaunchKernelGGL(kA_bits,  dim3(8192), dim3(256), 0, stream, adj, adjbT);
  hipLaunchKernelGGL(k0_wht,   dim3(512),  dim3(256), 0, stream, Wh, WhT);
  hipLaunchKernelGGL(k1_h,     dim3(1024), dim3(256), 0, stream, x, WhT, ah, H, f1, f2);
  hipLaunchKernelGGL(kE_exp,   dim3(128),  dim3(256), 0, stream, f1, f2, e1p, e2p);
  hipLaunchKernelGGL(k2a_htT,  dim3(512),  dim3(256), 0, stream, H, HT);
  hipLaunchKernelGGL(k2b_fill, dim3(256),  dim3(256), 0, stream, HT);
  hipLaunchKernelGGL(k3_attA,  dim3(512),  dim3(256), 0, stream, adjbT, HT, e1p, e2p, accA);
  hipLaunchKernelGGL(k4_redA,  dim3(8192), dim3(256), 0, stream, accA, xcat);
  hipLaunchKernelGGL(k5_h2,    dim3(512),  dim3(256), 0, stream, xcat, Wo, ao, h2T, e1op, e2op);
  hipLaunchKernelGGL(k6_attB,  dim3(512),  dim3(256), 0, stream, adjbT, h2T, e1op, e2op, accB);
  hipLaunchKernelGGL(k7_redB,  dim3(512),  dim3(256), 0, stream, accB, out);
}